// Round 7
// baseline (412.557 us; speedup 1.0000x reference)
//
#include <hip/hip_runtime.h>
#include <hip/hip_bf16.h>
#include <cstdint>
#include <cstddef>

#define B_   2
#define N_   2048
#define D_   2048
#define H_   16
#define HD_  128
#define C_   128
#define NC_  16
#define M_   4096   // B_*N_
#define QKVG_ 8192  // fused projection width: q|k|v|gate

typedef __attribute__((ext_vector_type(8))) short bf16x8;
typedef __attribute__((ext_vector_type(4))) float f32x4;
typedef __attribute__((ext_vector_type(16))) float f32x16;

__device__ __forceinline__ uint16_t f2bf(float f){
  __hip_bfloat16 h = __float2bfloat16(f);
  return *reinterpret_cast<uint16_t*>(&h);
}
__device__ __forceinline__ float bf2f(uint16_t u){
  union { uint32_t i; float f; } v; v.i = ((uint32_t)u) << 16; return v.f;
}

// async global->LDS, 16B per lane. LDS dest must be wave-uniform base + lane*16.
__device__ __forceinline__ void async16(const uint16_t* g, uint16_t* l){
  __builtin_amdgcn_global_load_lds(
      (const __attribute__((address_space(1))) void*)g,
      (__attribute__((address_space(3))) void*)l, 16, 0, 0);
}

// [128][128] attention-tile swizzle v2: chunk = (j>>3) ^ e ^ (e>>3).
// The e>>3 term spreads banks when a thread writes 8 consecutive-e elements
// (vectorized staging): per-write-instr banks ~4-way (was same-bank under the
// old (j>>3)^e form). Frag reads (lanes over lr rows, kq chunks) stay evenly
// spread. swz is used by BOTH writes and reads in chunk_state/attn, so the
// change is correctness-neutral by construction.
__device__ __forceinline__ int swz(int e, int j){
  return e*128 + ((((j >> 3) ^ e ^ (e >> 3)) & 15) << 3) + (j & 7);
}

// XCD-aware block swizzle (T1): 8 XCDs, nwg must be divisible by 8 (all our
// grids are). Each XCD gets a contiguous raster chunk -> A-panel L2 reuse.
__device__ __forceinline__ void xcd_swz(int& bx, int& by){
  const int gx = gridDim.x, nwg = gx*gridDim.y;
  int flat = by*gx + bx;
  if ((nwg & 7) == 0){
    const int cpx = nwg >> 3;
    flat = (flat & 7)*cpx + (flat >> 3);
  }
  bx = flat % gx; by = flat / gx;
}

// -------------------- all weight prep + x cast in ONE launch (grid.z = 0..6)
__global__ __launch_bounds__(256)
void prep_weights(const float* __restrict__ Wq, const float* __restrict__ Wk,
                  const float* __restrict__ Wv, const float* __restrict__ Wo,
                  const float* __restrict__ Wg2, const float* __restrict__ Wg1,
                  uint16_t* __restrict__ WT, uint16_t* __restrict__ WoT,
                  uint16_t* __restrict__ Wg2T, uint16_t* __restrict__ Wg1b,
                  const float* __restrict__ x, uint16_t* __restrict__ xb)
{
  const int z = blockIdx.z;
  const int tx = threadIdx.x & 31;
  const int ty = threadIdx.x >> 5;   // 0..7
  __shared__ uint16_t tile[32][33];

  if (z == 6){                       // cast x [4096][2048] fp32 -> bf16, float4
    const int r0 = blockIdx.y*64, c0 = blockIdx.x*32;
    const int cx = (threadIdx.x & 7)*4, ry = threadIdx.x >> 3;   // 32 rows x 8 quads
    #pragma unroll
    for (int rr = 0; rr < 2; ++rr){
      int r = r0 + ry + rr*32;
      float4 f = *(const float4*)(x + (size_t)r*D_ + c0 + cx);
      ushort4 u;
      u.x = f2bf(f.x); u.y = f2bf(f.y); u.z = f2bf(f.z); u.w = f2bf(f.w);
      *(ushort4*)(xb + (size_t)r*D_ + c0 + cx) = u;
    }
    return;
  }

  if (z == 5){                       // straight cast Wg1
    if (blockIdx.x >= 4) return;
    const int r0 = blockIdx.y*32, c0 = blockIdx.x*32;
    #pragma unroll
    for (int rr = 0; rr < 4; ++rr){
      int r = r0 + ty + rr*8;
      Wg1b[(size_t)r*HD_ + c0 + tx] = f2bf(Wg1[(size_t)r*HD_ + c0 + tx]);
    }
    return;
  }

  const float* src; uint16_t* dst; int R, Cc;
  if (z < 3)      { src = (z==0)?Wq:(z==1)?Wk:Wv; dst = WT + (size_t)z*D_*D_; R = D_; Cc = D_; }
  else if (z == 3){ src = Wo;  dst = WoT;  R = D_;  Cc = D_; }
  else            { if (blockIdx.y >= 4) return;
                    src = Wg2; dst = Wg2T; R = HD_; Cc = D_; }

  const int r0 = blockIdx.y*32, c0 = blockIdx.x*32;
  #pragma unroll
  for (int rr = 0; rr < 4; ++rr){
    int r = ty + rr*8;
    tile[r][tx] = f2bf(src[(size_t)(r0 + r)*Cc + c0 + tx]);
  }
  __syncthreads();
  #pragma unroll
  for (int rr = 0; rr < 4; ++rr){
    int r = ty + rr*8;
    dst[(size_t)(c0 + r)*R + r0 + tx] = tile[tx][r];
  }
}

// ---------------------- GEMM v2: 128x128, 4 waves (small-K Wg GEMM + Wo GEMM)
template<int ACT, int OUTBF>
__global__ __launch_bounds__(256)
void gemm_bt2(const uint16_t* __restrict__ A, const uint16_t* __restrict__ Bt,
              void* __restrict__ Cout, int M, int Ncols, int K, int klen)
{
  __shared__ __align__(16) uint16_t As[128*64];
  __shared__ __align__(16) uint16_t Bs[128*64];
  const int t    = threadIdx.x;
  const int lane = t & 63, wave = t >> 6;
  const int wm = wave >> 1, wn = wave & 1;
  const int row0 = wm*64, col0 = wn*64;
  const int lm = lane & 31, lh = lane >> 5;

  int bx = blockIdx.x, by = blockIdx.y;
  xcd_swz(bx, by);

  const uint16_t* Ap = A  + (size_t)(by*128)*K;
  const uint16_t* Bp = Bt + (size_t)(bx*128)*K;
  const int kbeg = blockIdx.z * klen;

  f32x16 acc[2][2];
  #pragma unroll
  for (int i = 0; i < 2; ++i)
    #pragma unroll
    for (int j = 0; j < 2; ++j)
      #pragma unroll
      for (int r = 0; r < 16; ++r) acc[i][j][r] = 0.f;

  const int srow = t >> 3;
  const int gch  = (t & 7) ^ (srow & 7);
  const size_t aoff0 = (size_t)srow*K + gch*8;

  for (int k0 = kbeg; k0 < kbeg + klen; k0 += 64){
    #pragma unroll
    for (int c = 0; c < 4; ++c){
      async16(Ap + (size_t)(c*32)*K + aoff0 + k0, As + c*2048 + t*8);
      async16(Bp + (size_t)(c*32)*K + aoff0 + k0, Bs + c*2048 + t*8);
    }
    __syncthreads();
    #pragma unroll
    for (int kh = 0; kh < 4; ++kh){
      bf16x8 af[2], bfr[2];
      const int ch = kh*2 + lh;
      #pragma unroll
      for (int i = 0; i < 2; ++i){
        int r = row0 + i*32 + lm;
        af[i] = *(const bf16x8*)(As + r*64 + ((ch ^ (r & 7)) << 3));
      }
      #pragma unroll
      for (int j = 0; j < 2; ++j){
        int r = col0 + j*32 + lm;
        bfr[j] = *(const bf16x8*)(Bs + r*64 + ((ch ^ (r & 7)) << 3));
      }
      #pragma unroll
      for (int i = 0; i < 2; ++i)
        #pragma unroll
        for (int j = 0; j < 2; ++j)
          acc[i][j] = __builtin_amdgcn_mfma_f32_32x32x16_bf16(af[i], bfr[j], acc[i][j], 0, 0, 0);
    }
    __syncthreads();
  }

  const int mode = (ACT == 3) ? ((bx < 48) ? 1 : 2) : ACT;
  uint16_t* outb = (uint16_t*)Cout;
  float*    outf = (float*)Cout + (OUTBF ? 0 : (size_t)blockIdx.z*M*Ncols);
  #pragma unroll
  for (int i = 0; i < 2; ++i){
    #pragma unroll
    for (int j = 0; j < 2; ++j){
      #pragma unroll
      for (int r = 0; r < 16; ++r){
        int row = by*128 + row0 + i*32 + (r & 3) + 8*(r >> 2) + 4*lh;
        int col = bx*128 + col0 + j*32 + lm;
        float v = acc[i][j][r];
        if (mode == 1)      v = v / (1.f + __expf(-v));
        else if (mode == 2) v = 1.f / (1.f + __expf(-v));
        size_t off = (size_t)row*Ncols + col;
        if (OUTBF) outb[off] = f2bf(v);
        else       outf[off] = v;
      }
    }
  }
}

// ============================================================ GEMM v7: 256x256
// Ring-4 + one-phase read-ahead (R6 verified: 39% MfmaUtil, best schedule of 6
// tried). This round: + XCD swizzle (T1) only — schedule frozen.
template<int ACT, int OUTBF>
__global__ __launch_bounds__(512, 2)
void gemm256(const uint16_t* __restrict__ A, const uint16_t* __restrict__ Bt,
             void* __restrict__ Cout, int M, int Ncols, int K, int klen)
{
  __shared__ __align__(16) uint16_t As[4*256*32];   // 64 KiB: ring of 4
  __shared__ __align__(16) uint16_t Bs[4*256*32];   // 64 KiB
  const int t    = threadIdx.x;
  const int lane = t & 63, wave = t >> 6;
  const int wm = wave >> 2, wn = wave & 3;          // 2M x 4N wave grid
  const int lm = lane & 31, lh = lane >> 5;
  const int sel = (lm >> 1) & 3;

  int bx = blockIdx.x, by = blockIdx.y;
  xcd_swz(bx, by);

  // element offsets inside one 8192-elem buffer: row*32 + slot*8
  int arow[4], brow[2], sl[2];
  #pragma unroll
  for (int m = 0; m < 4; ++m) arow[m] = (wm*128 + m*32 + lm)*32;
  #pragma unroll
  for (int n = 0; n < 2; ++n) brow[n] = (wn*64 + n*32 + lm)*32;
  #pragma unroll
  for (int kk = 0; kk < 2; ++kk) sl[kk] = ((kk*2 + lh) ^ sel) << 3;

  const uint16_t* Ap = A  + (size_t)(by*256)*K;
  const uint16_t* Bp = Bt + (size_t)(bx*256)*K;
  const int kbeg = blockIdx.z*klen;
  const int NTK  = klen >> 5;                       // BK=32 K-steps (NTK >= 4)

  const int gch  = (t & 3) ^ ((t >> 3) & 3);
  const size_t srcoff = (size_t)(t >> 2)*K + gch*8;
  const int ldst = t*8;

  f32x16 acc[4][2];
  #pragma unroll
  for (int m = 0; m < 4; ++m)
    #pragma unroll
    for (int n = 0; n < 2; ++n)
      #pragma unroll
      for (int r = 0; r < 16; ++r) acc[m][n][r] = 0.f;

  auto stageA = [&](int j){
    const size_t ko = (size_t)kbeg + (size_t)j*32;
    uint16_t* d = As + (j & 3)*8192 + ldst;
    async16(Ap + srcoff + ko, d);
    async16(Ap + (size_t)128*K + srcoff + ko, d + 4096);
  };
  auto stageB = [&](int j){
    const size_t ko = (size_t)kbeg + (size_t)j*32;
    uint16_t* d = Bs + (j & 3)*8192 + ldst;
    async16(Bp + srcoff + ko, d);
    async16(Bp + (size_t)128*K + srcoff + ko, d + 4096);
  };

  // prologue: stage K-steps 0..2; vmcnt(4) certifies steps 0 AND 1.
  stageA(0); stageB(0);
  stageA(1); stageB(1);
  stageA(2); stageB(2);
  asm volatile("s_waitcnt vmcnt(4)" ::: "memory");
  __builtin_amdgcn_s_barrier();
  asm volatile("" ::: "memory");

  bf16x8 af0[4], bf0[2], af1[4], bf1[2];
  #pragma unroll
  for (int m = 0; m < 4; ++m) af0[m] = *(const bf16x8*)(As + arow[m] + sl[0]);
  #pragma unroll
  for (int n = 0; n < 2; ++n) bf0[n] = *(const bf16x8*)(Bs + brow[n] + sl[0]);

  for (int kt = 0; kt < NTK; ++kt){
    const uint16_t* Ac = As + (kt & 3)*8192;
    const uint16_t* Bc = Bs + (kt & 3)*8192;
    const uint16_t* An = As + ((kt + 1) & 3)*8192;
    const uint16_t* Bn = Bs + ((kt + 1) & 3)*8192;

    // ---- P0: issue reads for S1 (cur, kk1); stage A(kt+3); wait S0; MFMA S0
    #pragma unroll
    for (int m = 0; m < 4; ++m) af1[m] = *(const bf16x8*)(Ac + arow[m] + sl[1]);
    #pragma unroll
    for (int n = 0; n < 2; ++n) bf1[n] = *(const bf16x8*)(Bc + brow[n] + sl[1]);
    if (kt + 3 < NTK) stageA(kt + 3);
    asm volatile("s_waitcnt lgkmcnt(6)" ::: "memory");   // drains S0's reads only
    __builtin_amdgcn_sched_barrier(0);                   // rule #18
    __builtin_amdgcn_s_setprio(1);
    #pragma unroll
    for (int m = 0; m < 4; ++m)
      #pragma unroll
      for (int n = 0; n < 2; ++n)
        acc[m][n] = __builtin_amdgcn_mfma_f32_32x32x16_bf16(af0[m], bf0[n], acc[m][n], 0, 0, 0);
    __builtin_amdgcn_s_setprio(0);

    // ---- P1: issue reads for next S0 (next buf, kk0); stage B(kt+3); wait S1
    if (kt + 1 < NTK){
      #pragma unroll
      for (int m = 0; m < 4; ++m) af0[m] = *(const bf16x8*)(An + arow[m] + sl[0]);
      #pragma unroll
      for (int n = 0; n < 2; ++n) bf0[n] = *(const bf16x8*)(Bn + brow[n] + sl[0]);
    }
    if (kt + 3 < NTK) stageB(kt + 3);
    if (kt + 1 < NTK) asm volatile("s_waitcnt lgkmcnt(6)" ::: "memory");
    else              asm volatile("s_waitcnt lgkmcnt(0)" ::: "memory");
    __builtin_amdgcn_sched_barrier(0);
    __builtin_amdgcn_s_setprio(1);
    #pragma unroll
    for (int m = 0; m < 4; ++m)
      #pragma unroll
      for (int n = 0; n < 2; ++n)
        acc[m][n] = __builtin_amdgcn_mfma_f32_32x32x16_bf16(af1[m], bf1[n], acc[m][n], 0, 0, 0);
    __builtin_amdgcn_s_setprio(0);

    if (kt + 3 < NTK)       asm volatile("s_waitcnt vmcnt(4)" ::: "memory");
    else if (kt + 3 == NTK) asm volatile("s_waitcnt vmcnt(0)" ::: "memory");
    __builtin_amdgcn_s_barrier();
    asm volatile("" ::: "memory");
  }

  // epilogue. 32x32 C/D layout: col = lane&31, row = (r&3) + 8*(r>>2) + 4*lh
  const int mode = (ACT == 3) ? (((bx << 8) < Ncols - 2048) ? 1 : 2) : ACT;
  uint16_t* outb = (uint16_t*)Cout;
  float*    outf = (float*)Cout + (OUTBF ? 0 : (size_t)blockIdx.z*M*Ncols);
  #pragma unroll
  for (int m = 0; m < 4; ++m){
    #pragma unroll
    for (int n = 0; n < 2; ++n){
      #pragma unroll
      for (int r = 0; r < 16; ++r){
        int row = by*256 + wm*128 + m*32 + (r & 3) + 8*(r >> 2) + 4*lh;
        int col = bx*256 + wn*64  + n*32 + lm;
        float v = acc[m][n][r];
        if (mode == 1)      v = v / (1.f + __expf(-v));
        else if (mode == 2) v = 1.f / (1.f + __expf(-v));
        size_t off = (size_t)row*Ncols + col;
        if (OUTBF) outb[off] = f2bf(v);
        else       outf[off] = v;
      }
    }
  }
}

// ---------------------------------------------- per-chunk state contribution
// Staging vectorized (R7): bf16x8 global loads (16B/lane coalesced, 8x fewer
// VMEM instrs than scalar) + 8 ds_write_b16 through swz v2 (~4-way banks).
__global__ __launch_bounds__(256)
void chunk_state_kernel(const uint16_t* __restrict__ qkvg,
                        const float* __restrict__ log_decay, uint16_t* __restrict__ MsumT)
{
  __shared__ __align__(16) uint16_t vT[128*128];
  __shared__ __align__(16) uint16_t kT[128*128];
  const int h = blockIdx.x, b = blockIdx.y, ic = blockIdx.z;
  const int t    = threadIdx.x;
  const int lane = t & 63, wave = t >> 6;
  const int wm = wave >> 1, wn = wave & 1;
  const int e0 = wm*64, d0 = wn*64;
  const int lr = lane & 15, kq = lane >> 4;
  const float ld = log_decay[h];
  const size_t rowbase = (size_t)b*N_ + (size_t)ic*C_;
  const uint16_t* kb = qkvg + (size_t)D_;
  const uint16_t* vb = qkvg + (size_t)2*D_;

  #pragma unroll
  for (int it = 0; it < 8; ++it){
    int idx = t + it*256;                 // 0..2047
    int j = idx >> 4, ee = (idx & 15)*8;  // row j, e-chunk ee..ee+7
    const size_t g = (rowbase + j)*QKVG_ + h*HD_ + ee;
    bf16x8 kv = *(const bf16x8*)(kb + g);
    bf16x8 vv = *(const bf16x8*)(vb + g);
    float dk = __expf(ld * (float)(C_ - 1 - j));
    #pragma unroll
    for (int u = 0; u < 8; ++u){
      int s = swz(ee + u, j);
      vT[s] = (uint16_t)(unsigned short)vv[u];
      kT[s] = f2bf(bf2f((uint16_t)(unsigned short)kv[u]) * dk);
    }
  }
  __syncthreads();

  const f32x4 zero = {0.f, 0.f, 0.f, 0.f};
  f32x4 acc[4][4];
  #pragma unroll
  for (int i = 0; i < 4; ++i)
    #pragma unroll
    for (int j = 0; j < 4; ++j) acc[i][j] = zero;

  #pragma unroll
  for (int kt = 0; kt < 4; ++kt){
    bf16x8 af[4], bfr[4];
    #pragma unroll
    for (int i = 0; i < 4; ++i)
      af[i]  = *(const bf16x8*)(vT + swz(e0 + i*16 + lr, kt*32 + kq*8));
    #pragma unroll
    for (int j = 0; j < 4; ++j)
      bfr[j] = *(const bf16x8*)(kT + swz(d0 + j*16 + lr, kt*32 + kq*8));
    #pragma unroll
    for (int i = 0; i < 4; ++i)
      #pragma unroll
      for (int j = 0; j < 4; ++j)
        acc[i][j] = __builtin_amdgcn_mfma_f32_16x16x32_bf16(af[i], bfr[j], acc[i][j], 0, 0, 0);
  }

  uint16_t* Mout = MsumT + (((size_t)ic*B_ + b)*H_ + h)*(size_t)(HD_*HD_);
  #pragma unroll
  for (int i = 0; i < 4; ++i)
    #pragma unroll
    for (int j = 0; j < 4; ++j)
      #pragma unroll
      for (int r = 0; r < 4; ++r)
        Mout[(size_t)(e0 + i*16 + kq*4 + r)*HD_ + d0 + j*16 + lr] = f2bf(acc[i][j][r]);
}

// -------------------------------------------------- inter-chunk state scan
// Vectorized (R7): thread t owns 8 contiguous elems (bf16x8 load/store).
__global__ __launch_bounds__(256)
void scan_kernel(const uint16_t* __restrict__ MsumT, const float* __restrict__ log_decay,
                 uint16_t* __restrict__ StT)
{
  const int h = blockIdx.x, b = blockIdx.y;
  const float ld = log_decay[h];
  const float dS = __expf(ld * (float)C_);
  const size_t off = (size_t)blockIdx.z*2048 + (size_t)threadIdx.x*8;
  float cur[8];
  #pragma unroll
  for (int u = 0; u < 8; ++u) cur[u] = 0.f;
  for (int i = 0; i < NC_; ++i){
    const size_t base = (((size_t)i*B_ + b)*H_ + h)*(size_t)(HD_*HD_) + off;
    bf16x8 m = *(const bf16x8*)(MsumT + base);
    bf16x8 s;
    #pragma unroll
    for (int u = 0; u < 8; ++u) s[u] = (short)f2bf(cur[u]);
    *(bf16x8*)(StT + base) = s;
    #pragma unroll
    for (int u = 0; u < 8; ++u)
      cur[u] = cur[u]*dS + bf2f((uint16_t)(unsigned short)m[u]);
  }
}

// ------------------------------------------------------ intra-chunk attention
__global__ __launch_bounds__(256)
void attn_kernel(const uint16_t* __restrict__ qkvg, const uint16_t* __restrict__ StT,
                 const float* __restrict__ log_decay, float* __restrict__ o_attn)
{
  __shared__ __align__(16) uint16_t Ps[128*128];
  __shared__ __align__(16) uint16_t vT[128*128];
  const int h = blockIdx.x, b = blockIdx.y, ic = blockIdx.z;
  const int t    = threadIdx.x;
  const int lane = t & 63, wave = t >> 6;
  const int wm = wave >> 1, wn = wave & 1;
  const int row0 = wm*64, col0 = wn*64;
  const int lr = lane & 15, kq = lane >> 4;
  const float ld = log_decay[h];
  const size_t rowbase = (size_t)b*N_ + (size_t)ic*C_;
  const uint16_t* qb = qkvg;
  const uint16_t* kb = qkvg + (size_t)D_;
  const uint16_t* vb = qkvg + (size_t)2*D_;

  // vectorized vT staging (see chunk_state)
  #pragma unroll
  for (int it = 0; it < 8; ++it){
    int idx = t + it*256;
    int j = idx >> 4, ee = (idx & 15)*8;
    bf16x8 vv = *(const bf16x8*)(vb + (rowbase + j)*QKVG_ + h*HD_ + ee);
    #pragma unroll
    for (int u = 0; u < 8; ++u)
      vT[swz(ee + u, j)] = (uint16_t)(unsigned short)vv[u];
  }

  const f32x4 zero = {0.f, 0.f, 0.f, 0.f};
  f32x4 acc[4][4];
  #pragma unroll
  for (int i = 0; i < 4; ++i)
    #pragma unroll
    for (int j = 0; j < 4; ++j) acc[i][j] = zero;

  // phase A: P = (q @ k^T) ∘ Dm
  #pragma unroll
  for (int kt = 0; kt < 4; ++kt){
    bf16x8 af[4], bfr[4];
    #pragma unroll
    for (int i = 0; i < 4; ++i)
      af[i]  = *(const bf16x8*)(qb + (rowbase + row0 + i*16 + lr)*QKVG_ + h*HD_ + kt*32 + kq*8);
    #pragma unroll
    for (int j = 0; j < 4; ++j)
      bfr[j] = *(const bf16x8*)(kb + (rowbase + col0 + j*16 + lr)*QKVG_ + h*HD_ + kt*32 + kq*8);
    #pragma unroll
    for (int i = 0; i < 4; ++i)
      #pragma unroll
      for (int j = 0; j < 4; ++j)
        acc[i][j] = __builtin_amdgcn_mfma_f32_16x16x32_bf16(af[i], bfr[j], acc[i][j], 0, 0, 0);
  }
  #pragma unroll
  for (int i = 0; i < 4; ++i)
    #pragma unroll
    for (int j = 0; j < 4; ++j)
      #pragma unroll
      for (int r = 0; r < 4; ++r){
        int row = row0 + i*16 + kq*4 + r;
        int col = col0 + j*16 + lr;
        int dlt = row - col;
        float f = (dlt >= 0) ? __expf(ld * (float)dlt) : 0.f;
        Ps[swz(row, col)] = f2bf(acc[i][j][r] * f);
      }

  // phase B1: o2 = q @ S_start
  #pragma unroll
  for (int i = 0; i < 4; ++i)
    #pragma unroll
    for (int j = 0; j < 4; ++j) acc[i][j] = zero;
  const uint16_t* Sb = StT + (((size_t)ic*B_ + b)*H_ + h)*(size_t)(HD_*HD_);
  #pragma unroll
  for (int kt = 0; kt < 4; ++kt){
    bf16x8 af[4], bfr[4];
    #pragma unroll
    for (int i = 0; i < 4; ++i)
      af[i]  = *(const bf16x8*)(qb + (rowbase + row0 + i*16 + lr)*QKVG_ + h*HD_ + kt*32 + kq*8);
    #pragma unroll
    for (int j = 0; j < 4; ++j)
      bfr[j] = *(const bf16x8*)(Sb + (size_t)(col0 + j*16 + lr)*HD_ + kt*32 + kq*8);
    #pragma unroll
    for (int i = 0; i < 4; ++i)
      #pragma unroll
      for (int j = 0; j < 4; ++j)
        acc[i][j] = __builtin_amdgcn_mfma_f32_16x16x32_bf16(af[i], bfr[j], acc[i][j], 0, 0, 0);
  }
  #pragma unroll
  for (int i = 0; i < 4; ++i)
    #pragma unroll
    for (int r = 0; r < 4; ++r){
      float dqv = __expf(ld * (float)(row0 + i*16 + kq*4 + r + 1));
      #pragma unroll
      for (int j = 0; j < 4; ++j) acc[i][j][r] *= dqv;
    }

  __syncthreads();

  // phase B2: o += P @ v
  #pragma unroll
  for (int kt = 0; kt < 4; ++kt){
    bf16x8 af[4], bfr[4];
    #pragma unroll
    for (int i = 0; i < 4; ++i)
      af[i]  = *(const bf16x8*)(Ps + swz(row0 + i*16 + lr, kt*32 + kq*8));
    #pragma unroll
    for (int j = 0; j < 4; ++j)
      bfr[j] = *(const bf16x8*)(vT + swz(col0 + j*16 + lr, kt*32 + kq*8));
    #pragma unroll
    for (int i = 0; i < 4; ++i)
      #pragma unroll
      for (int j = 0; j < 4; ++j)
        acc[i][j] = __builtin_amdgcn_mfma_f32_16x16x32_bf16(af[i], bfr[j], acc[i][j], 0, 0, 0);
  }

  #pragma unroll
  for (int i = 0; i < 4; ++i)
    #pragma unroll
    for (int j = 0; j < 4; ++j)
      #pragma unroll
      for (int r = 0; r < 4; ++r){
        int row = row0 + i*16 + kq*4 + r;
        int col = col0 + j*16 + lr;
        o_attn[(rowbase + row)*D_ + h*HD_ + col] = acc[i][j][r];
      }
}

// --------------------------------------------- gate ⊙ + rmsnorm + cast bf16
__global__ __launch_bounds__(256)
void gate_norm_kernel(const float* __restrict__ o_attn, const uint16_t* __restrict__ qkvg,
                      const float* __restrict__ norm_w, uint16_t* __restrict__ on)
{
  const int row = blockIdx.x;
  const int t = threadIdx.x;
  const int c1 = t*4, c2 = 1024 + t*4;
  const float*    orow = o_attn + (size_t)row*D_;
  const uint16_t* grow = qkvg + (size_t)row*QKVG_ + 3*D_;
  float4  o1 = *(const float4*)(orow + c1);
  float4  o2 = *(const float4*)(orow + c2);
  ushort4 g1 = *(const ushort4*)(grow + c1);
  ushort4 g2 = *(const ushort4*)(grow + c2);
  float v[8];
  v[0] = o1.x*bf2f(g1.x); v[1] = o1.y*bf2f(g1.y); v[2] = o1.z*bf2f(g1.z); v[3] = o1.w*bf2f(g1.w);
  v[4] = o2.x*bf2f(g2.x); v[5] = o2.y*bf2f(g2.y); v[6] = o2.z*bf2f(g2.z); v[7] = o2.w*bf2f(g2.w);
  float s = 0.f;
  #pragma unroll
  for (int k = 0; k < 8; ++k) s += v[k]*v[k];
  #pragma unroll
  for (int off = 32; off > 0; off >>= 1) s += __shfl_down(s, off);
  __shared__ float red[4];
  if ((t & 63) == 0) red[t >> 6] = s;
  __syncthreads();
  float total = red[0] + red[1] + red[2] + red[3];
  float scale = rsqrtf(total * (1.f/(float)D_) + 1e-6f);
  float4 w1 = *(const float4*)(norm_w + c1);
  float4 w2 = *(const float4*)(norm_w + c2);
  ushort4 b1, b2;
  b1.x = f2bf(v[0]*scale*w1.x); b1.y = f2bf(v[1]*scale*w1.y);
  b1.z = f2bf(v[2]*scale*w1.z); b1.w = f2bf(v[3]*scale*w1.w);
  b2.x = f2bf(v[4]*scale*w2.x); b2.y = f2bf(v[5]*scale*w2.y);
  b2.z = f2bf(v[6]*scale*w2.z); b2.w = f2bf(v[7]*scale*w2.w);
  *(ushort4*)(on + (size_t)row*D_ + c1) = b1;
  *(ushort4*)(on + (size_t)row*D_ + c2) = b2;
}

// =============================================================== launch
extern "C" void kernel_launch(void* const* d_in, const int* in_sizes, int n_in,
                              void* d_out, int out_size, void* d_ws, size_t ws_size,
                              hipStream_t stream) {
  const float* x         = (const float*)d_in[0];
  const float* log_decay = (const float*)d_in[1];
  const float* Wq        = (const float*)d_in[2];
  const float* Wk        = (const float*)d_in[3];
  const float* Wv        = (const float*)d_in[4];
  const float* Wo        = (const float*)d_in[5];
  const float* Wg1       = (const float*)d_in[6];
  const float* Wg2       = (const float*)d_in[7];
  const float* norm_w    = (const float*)d_in[8];
  float* out = (float*)d_out;

  // workspace layout (~160 MB with aliasing)
  uint8_t* p = (uint8_t*)d_ws;
  uint16_t* xb    = (uint16_t*)p; p += (size_t)M_*D_*2;        // reused as `on`
  uint16_t* WT    = (uint16_t*)p; p += (size_t)QKVG_*D_*2;     // reused as o_att
  uint16_t* WoT   = (uint16_t*)p; p += (size_t)D_*D_*2;
  uint16_t* Wg1b  = (uint16_t*)p; p += (size_t)D_*HD_*2;
  uint16_t* Wg2T  = (uint16_t*)p; p += (size_t)D_*HD_*2;
  uint16_t* qkvg  = (uint16_t*)p; p += (size_t)M_*QKVG_*2;
  uint16_t* MsumT = (uint16_t*)p; p += (size_t)NC_*B_*H_*HD_*HD_*2;
  uint16_t* StT   = (uint16_t*)p; p += (size_t)NC_*B_*H_*HD_*HD_*2;
  float*    o_att = (float*)WT;
  uint16_t* on    = xb;

  // 1. all weight prep + x cast in ONE launch (z = 0..6)
  prep_weights<<<dim3(64, 64, 7), 256, 0, stream>>>(Wq, Wk, Wv, Wo, Wg2, Wg1,
                                                    WT, WoT, Wg2T, Wg1b, x, xb);

  // 2. Wg^T = (Wg1 @ Wg2)^T into WT slice 3 (small K=128: 128^2 kernel)
  gemm_bt2<0,1><<<dim3(D_/128, D_/128, 1), 256, 0, stream>>>(
      Wg2T, Wg1b, WT + (size_t)3*D_*D_, D_, D_, HD_, HD_);

  // 3. fused projection: [q|k|v|gate] = act(x @ [Wq|Wk|Wv|Wg]) — v7 + XCD swz
  gemm256<3,1><<<dim3(QKVG_/256, M_/256, 1), 512, 0, stream>>>(
      xb, WT, qkvg, M_, QKVG_, D_, D_);

  // 4. attention: chunk states -> scan -> intra-chunk
  chunk_state_kernel<<<dim3(H_, B_, NC_), 256, 0, stream>>>(qkvg, log_decay, MsumT);
  scan_kernel<<<dim3(H_, B_, 8), 256, 0, stream>>>(MsumT, log_decay, StT);
  attn_kernel<<<dim3(H_, B_, NC_), 256, 0, stream>>>(qkvg, StT, log_decay, o_att);

  // 5. gate + rmsnorm + final projection: single-pass 128^2 GEMM, fp32 direct
  gate_norm_kernel<<<M_, 256, 0, stream>>>(o_att, qkvg, norm_w, on);
  gemm_bt2<0,0><<<dim3(D_/128, M_/128, 1), 256, 0, stream>>>(
      on, WoT, out, M_, D_, D_, D_);
}